// Round 6
// baseline (40.045 us; speedup 1.0000x reference)
//
#include <hip/hip_runtime.h>
#include <hip/hip_bf16.h>
#include <stdint.h>

#define HS 4096
#define NE 64

using half8 = __attribute__((ext_vector_type(8))) _Float16;
using f32x4 = __attribute__((ext_vector_type(4))) float;

constexpr int KSPLIT = 8;
constexpr int KPS    = HS / KSPLIT;     // 512 k per split
constexpr int WPB    = 8;               // waves per block (512 threads)
constexpr int M_WAVE = 32;              // tokens per wave = 2 MFMA M-tiles
constexpr int M_BLK  = WPB * M_WAVE;    // 256 tokens per block
constexpr int SLOTS  = (KPS / 8) * 2 * NE;   // 8192 half8 per split slice

constexpr float XS  = 16.f;             // x scale (keeps xl out of f16 denormals)
constexpr float WSC = 1024.f;           // W scale (keeps Wl out of f16 denormals)
constexpr float INV_SCALE = 1.f / (XS * WSC);   // 2^-14, undone in finish

typedef __attribute__((address_space(3))) uint32_t lds_t;
typedef const __attribute__((address_space(1))) uint32_t glb_t;

// Prep: W fp32 -> scaled f16 hi/lo planes, laid out as the byte-image of the
// gemm's LDS slice per split: [split][(kgl*2+plane)*64 + expert] of half8.
__global__ __launch_bounds__(256)
void router_wconv(const float* __restrict__ W, half8* __restrict__ w16)
{
    const int idx = blockIdx.x * 256 + threadIdx.x;   // 0 .. 64*512-1
    const int e   = idx >> 9;                         // expert
    const int kg  = idx & 511;                        // global 8-float k-group
    const int s   = kg >> 6;                          // split
    const int kgl = kg & 63;                          // k-group within split
    const float* wp = W + (size_t)e * HS + (size_t)kg * 8;
    float4 u = *reinterpret_cast<const float4*>(wp);
    float4 v = *reinterpret_cast<const float4*>(wp + 4);
    float f[8] = {u.x, u.y, u.z, u.w, v.x, v.y, v.z, v.w};
    half8 h, lo;
    #pragma unroll
    for (int i = 0; i < 8; ++i) {
        float sv = f[i] * WSC;
        _Float16 hh = (_Float16)sv;
        h[i]  = hh;
        lo[i] = (_Float16)(sv - (float)hh);
    }
    const size_t base = (size_t)s * SLOTS + (size_t)(kgl * 2) * NE + e;
    w16[base]      = h;
    w16[base + NE] = lo;
}

// GEMM: per wave M=32 x N=64 x K=512, 3-term split-f16 MFMA accumulation.
// PRECONV: stage pre-converted W planes via global_load_lds (pure DMA).
template<bool PRECONV>
__global__ __launch_bounds__(512, 1)
void router_gemm(const float* __restrict__ x, const float* __restrict__ W,
                 const half8* __restrict__ w16, float* __restrict__ ws,
                 int n_tokens)
{
    __shared__ half8 Wl8[SLOTS];                     // 128 KiB

    const int tid = threadIdx.x;
    const int l   = tid & 63;
    const int wv  = __builtin_amdgcn_readfirstlane(tid >> 6);
    const int g   = l >> 4;              // k-group 0..3
    const int e   = l & 15;              // row/col within tile
    const int k0  = blockIdx.y * KPS;

    if (PRECONV) {
        const half8* src = w16 + (size_t)blockIdx.y * SLOTS;
        #pragma unroll
        for (int r = 0; r < SLOTS / 512; ++r)        // 16 rounds x 8 KiB
            __builtin_amdgcn_global_load_lds((glb_t*)(src + r * 512 + tid),
                                             (lds_t*)&Wl8[r * 512 + tid], 16, 0, 0);
        asm volatile("s_waitcnt vmcnt(0)" ::: "memory");
    } else {
        // fallback: in-kernel convert (R5 path)
        const int se = tid >> 3;
        const int sc = tid & 7;
        #pragma unroll
        for (int j = 0; j < 8; ++j) {
            const float* wp = W + (size_t)se * HS + k0 + sc * 8 + j * 64;
            float4 u = *reinterpret_cast<const float4*>(wp);
            float4 v = *reinterpret_cast<const float4*>(wp + 4);
            const int kg = sc + j * 8;
            float f[8] = {u.x, u.y, u.z, u.w, v.x, v.y, v.z, v.w};
            half8 h, lo;
            #pragma unroll
            for (int i = 0; i < 8; ++i) {
                float s = f[i] * WSC;
                _Float16 hh = (_Float16)s;
                h[i]  = hh;
                lo[i] = (_Float16)(s - (float)hh);
            }
            Wl8[(kg * 2 + 0) * NE + se] = h;
            Wl8[(kg * 2 + 1) * NE + se] = lo;
        }
    }
    __syncthreads();

    const int m0 = blockIdx.x * M_BLK + wv * M_WAVE;
    const float* xr0 = x + (size_t)(m0 + e) * HS + k0 + g * 8;   // M-tile 0
    const float* xr1 = xr0 + (size_t)16 * HS;                    // M-tile 1

    f32x4 acc[2][4];
    #pragma unroll
    for (int i = 0; i < 2; ++i)
        #pragma unroll
        for (int j = 0; j < 4; ++j) acc[i][j] = (f32x4){0.f, 0.f, 0.f, 0.f};

    // depth-2 x prefetch pipeline (named regs, static indices only)
    float4 a00 = *reinterpret_cast<const float4*>(xr0);
    float4 a01 = *reinterpret_cast<const float4*>(xr0 + 4);
    float4 a10 = *reinterpret_cast<const float4*>(xr1);
    float4 a11 = *reinterpret_cast<const float4*>(xr1 + 4);
    float4 b00 = *reinterpret_cast<const float4*>(xr0 + 32);
    float4 b01 = *reinterpret_cast<const float4*>(xr0 + 36);
    float4 b10 = *reinterpret_cast<const float4*>(xr1 + 32);
    float4 b11 = *reinterpret_cast<const float4*>(xr1 + 36);

    constexpr int NKS = KPS / 32;                    // 16 k-steps
    #pragma unroll 2
    for (int ks = 0; ks < NKS; ++ks) {
        float4 d00 = b00, d01 = b01, d10 = b10, d11 = b11;
        if (ks + 2 < NKS) {
            const float* p0 = xr0 + (ks + 2) * 32;
            const float* p1 = xr1 + (ks + 2) * 32;
            d00 = *reinterpret_cast<const float4*>(p0);
            d01 = *reinterpret_cast<const float4*>(p0 + 4);
            d10 = *reinterpret_cast<const float4*>(p1);
            d11 = *reinterpret_cast<const float4*>(p1 + 4);
        }

        // B fragments from LDS (hi/lo planes), same (g,j)->k map as A
        const int sb = (ks * 4 + g) * 2;
        half8 bh[4], bl[4];
        #pragma unroll
        for (int nt = 0; nt < 4; ++nt) {
            bh[nt] = Wl8[(sb + 0) * NE + nt * 16 + e];
            bl[nt] = Wl8[(sb + 1) * NE + nt * 16 + e];
        }

        // A fragments: fp32 -> scaled f16 hi/lo
        half8 ah0, al0, ah1, al1;
        {
            float f0[8] = {a00.x, a00.y, a00.z, a00.w, a01.x, a01.y, a01.z, a01.w};
            float f1[8] = {a10.x, a10.y, a10.z, a10.w, a11.x, a11.y, a11.z, a11.w};
            #pragma unroll
            for (int i = 0; i < 8; ++i) {
                float s0 = f0[i] * XS; _Float16 h0 = (_Float16)s0;
                ah0[i] = h0; al0[i] = (_Float16)(s0 - (float)h0);
                float s1 = f1[i] * XS; _Float16 h1 = (_Float16)s1;
                ah1[i] = h1; al1[i] = (_Float16)(s1 - (float)h1);
            }
        }

        // 3-term split-f16 accumulation: xh*Wh + xl*Wh + xh*Wl
        #pragma unroll
        for (int nt = 0; nt < 4; ++nt) {
            acc[0][nt] = __builtin_amdgcn_mfma_f32_16x16x32_f16(ah0, bh[nt], acc[0][nt], 0, 0, 0);
            acc[0][nt] = __builtin_amdgcn_mfma_f32_16x16x32_f16(al0, bh[nt], acc[0][nt], 0, 0, 0);
            acc[0][nt] = __builtin_amdgcn_mfma_f32_16x16x32_f16(ah0, bl[nt], acc[0][nt], 0, 0, 0);
            acc[1][nt] = __builtin_amdgcn_mfma_f32_16x16x32_f16(ah1, bh[nt], acc[1][nt], 0, 0, 0);
            acc[1][nt] = __builtin_amdgcn_mfma_f32_16x16x32_f16(al1, bh[nt], acc[1][nt], 0, 0, 0);
            acc[1][nt] = __builtin_amdgcn_mfma_f32_16x16x32_f16(ah1, bl[nt], acc[1][nt], 0, 0, 0);
        }

        a00 = b00; a01 = b01; a10 = b10; a11 = b11;
        b00 = d00; b01 = d01; b10 = d10; b11 = d11;
    }

    // epilogue: C layout col=lane&15 (expert), row=(lane>>4)*4+reg (token)
    #pragma unroll
    for (int mt = 0; mt < 2; ++mt)
        #pragma unroll
        for (int nt = 0; nt < 4; ++nt)
            #pragma unroll
            for (int r = 0; r < 4; ++r) {
                const int tok = m0 + mt * 16 + g * 4 + r;
                const int ex  = nt * 16 + e;
                ws[((size_t)blockIdx.y * n_tokens + tok) * NE + ex] = acc[mt][nt][r];
            }
}

// Finish: reduce k-splits, unscale, softmax, top-2. One wave per token.
__global__ __launch_bounds__(256)
void router_finish(const float* __restrict__ ws, float* __restrict__ out,
                   int n_tokens)
{
    const int lane  = threadIdx.x & 63;
    const int token = blockIdx.x * 4 + (threadIdx.x >> 6);
    if (token >= n_tokens) return;

    float v = 0.f;
    #pragma unroll
    for (int s = 0; s < KSPLIT; ++s)
        v += ws[(size_t)s * n_tokens * NE + (size_t)token * NE + lane];
    v *= INV_SCALE;                                   // undo 2^14 input scaling

    float m1 = v;
    #pragma unroll
    for (int off = 32; off >= 1; off >>= 1) m1 = fmaxf(m1, __shfl_xor(m1, off));
    unsigned long long b1 = __ballot(v == m1);        // lowest-index tie-break
    int i1 = __ffsll(b1) - 1;

    const float NINF = __int_as_float(0xff800000);
    float vx = (lane == i1) ? NINF : v;
    float m2 = vx;
    #pragma unroll
    for (int off = 32; off >= 1; off >>= 1) m2 = fmaxf(m2, __shfl_xor(m2, off));
    unsigned long long b2 = __ballot(vx == m2);
    int i2 = __ffsll(b2) - 1;

    float s = __expf(v - m1);
    #pragma unroll
    for (int off = 32; off >= 1; off >>= 1) s += __shfl_xor(s, off);

    if (lane == 0) {
        float inv = 1.0f / s;
        out[(size_t)token * 2 + 0] = inv;
        out[(size_t)token * 2 + 1] = __expf(m2 - m1) * inv;
        out[(size_t)n_tokens * 2 + (size_t)token * 2 + 0] = (float)i1;
        out[(size_t)n_tokens * 2 + (size_t)token * 2 + 1] = (float)i2;
    }
}

extern "C" void kernel_launch(void* const* d_in, const int* in_sizes, int n_in,
                              void* d_out, int out_size, void* d_ws, size_t ws_size,
                              hipStream_t stream)
{
    const float* x = (const float*)d_in[0];
    const float* W = (const float*)d_in[1];
    float* out = (float*)d_out;

    const int n_tokens = in_sizes[0] / HS;            // 8192
    const size_t part_bytes = (size_t)KSPLIT * n_tokens * NE * sizeof(float);  // 16 MiB
    const size_t w16_bytes  = (size_t)KSPLIT * SLOTS * sizeof(half8);          // 1 MiB

    float* ws_part = (float*)d_ws;
    half8* w16     = (half8*)((char*)d_ws + part_bytes);
    const bool preconv = ws_size >= part_bytes + w16_bytes;

    dim3 grid1(n_tokens / M_BLK, KSPLIT);             // (32, 8) = 256 blocks, 1/CU
    if (preconv) {
        router_wconv<<<NE * (HS / 8) / 256, 256, 0, stream>>>(W, w16);
        router_gemm<true><<<grid1, 512, 0, stream>>>(x, W, w16, ws_part, n_tokens);
    } else {
        router_gemm<false><<<grid1, 512, 0, stream>>>(x, W, w16, ws_part, n_tokens);
    }

    dim3 grid2((n_tokens + 3) / 4);
    router_finish<<<grid2, 256, 0, stream>>>(ws_part, out, n_tokens);
}